// Round 1
// baseline (248.246 us; speedup 1.0000x reference)
//
#include <hip/hip_runtime.h>
#include <hip/hip_bf16.h>
#include <math.h>

// Problem dims (fixed)
#define BB 4
#define TT 4096
#define DM 1024
#define DS 256
#define MROWS (BB*TT)        // 16384

// SGEMM tiling
#define BM 128
#define BN 128
#define BK 16

// Scan chunking
#define LCH 32               // chunk length
#define NCH (TT/LCH)         // 128 chunks

// C = epilogue(A @ B + bias), A:[M,K] row-major, B:[K,N] row-major.
// epilogue: v = acc + bias[n]; if (scale) v *= scale[n];
__global__ __launch_bounds__(256) void sgemm_kernel(
    const float* __restrict__ A, const float* __restrict__ B, float* __restrict__ C,
    int M, int N, int K,
    const float* __restrict__ bias, const float* __restrict__ scale)
{
    __shared__ float As[BK][BM + 4];
    __shared__ float Bs[BK][BN + 4];

    const int tid = threadIdx.x;
    const int bm = blockIdx.x, bn = blockIdx.y;

    // A-tile load: 128x16 floats = 512 float4; thread t -> float4 (t%4) of row t/4, rows r and r+64
    const int arow = tid >> 2;            // 0..63
    const int acol = (tid & 3) << 2;      // 0,4,8,12
    // B-tile load: 16x128 floats = 512 float4; thread t -> row t/32 (0..7) and +8, col4 (t%32)*4
    const int brow = tid >> 5;            // 0..7
    const int bcol = (tid & 31) << 2;     // 0..124

    const int ty = tid >> 4, tx = tid & 15;

    const float* Ap = A + (size_t)(bm * BM + arow) * K + acol;
    const float* Bp = B + (size_t)brow * N + (size_t)bn * BN + bcol;

    float acc[8][8];
#pragma unroll
    for (int i = 0; i < 8; i++)
#pragma unroll
        for (int j = 0; j < 8; j++) acc[i][j] = 0.0f;

    for (int k0 = 0; k0 < K; k0 += BK) {
        // prefetch to registers before the barrier
        float4 a0 = *(const float4*)(Ap + k0);
        float4 a1 = *(const float4*)(Ap + (size_t)64 * K + k0);
        float4 b0 = *(const float4*)(Bp + (size_t)k0 * N);
        float4 b1 = *(const float4*)(Bp + (size_t)(k0 + 8) * N);

        if (k0) __syncthreads();   // previous iter's LDS reads must be done

        As[acol + 0][arow] = a0.x; As[acol + 1][arow] = a0.y;
        As[acol + 2][arow] = a0.z; As[acol + 3][arow] = a0.w;
        As[acol + 0][arow + 64] = a1.x; As[acol + 1][arow + 64] = a1.y;
        As[acol + 2][arow + 64] = a1.z; As[acol + 3][arow + 64] = a1.w;
        *(float4*)&Bs[brow][bcol] = b0;
        *(float4*)&Bs[brow + 8][bcol] = b1;

        __syncthreads();

#pragma unroll
        for (int k = 0; k < BK; k++) {
            float4 ar0 = *(const float4*)&As[k][ty * 4];
            float4 ar1 = *(const float4*)&As[k][ty * 4 + 64];
            float4 br0 = *(const float4*)&Bs[k][tx * 4];
            float4 br1 = *(const float4*)&Bs[k][tx * 4 + 64];
            float a[8] = {ar0.x, ar0.y, ar0.z, ar0.w, ar1.x, ar1.y, ar1.z, ar1.w};
            float bb[8] = {br0.x, br0.y, br0.z, br0.w, br1.x, br1.y, br1.z, br1.w};
#pragma unroll
            for (int i = 0; i < 8; i++)
#pragma unroll
                for (int j = 0; j < 8; j++)
                    acc[i][j] = fmaf(a[i], bb[j], acc[i][j]);
        }
    }

    // epilogue
    const int cbase = bn * BN + tx * 4;
    float4 bi0 = *(const float4*)&bias[cbase];
    float4 bi1 = *(const float4*)&bias[cbase + 64];
    float4 sc0 = make_float4(1.f, 1.f, 1.f, 1.f), sc1 = sc0;
    if (scale) {
        sc0 = *(const float4*)&scale[cbase];
        sc1 = *(const float4*)&scale[cbase + 64];
    }
#pragma unroll
    for (int i = 0; i < 8; i++) {
        int r = bm * BM + ((i < 4) ? (ty * 4 + i) : (64 + ty * 4 + (i - 4)));
        float4 v0, v1;
        v0.x = (acc[i][0] + bi0.x) * sc0.x;
        v0.y = (acc[i][1] + bi0.y) * sc0.y;
        v0.z = (acc[i][2] + bi0.z) * sc0.z;
        v0.w = (acc[i][3] + bi0.w) * sc0.w;
        v1.x = (acc[i][4] + bi1.x) * sc1.x;
        v1.y = (acc[i][5] + bi1.y) * sc1.y;
        v1.z = (acc[i][6] + bi1.z) * sc1.z;
        v1.w = (acc[i][7] + bi1.w) * sc1.w;
        *(float4*)&C[(size_t)r * N + cbase] = v0;
        *(float4*)&C[(size_t)r * N + cbase + 64] = v1;
    }
}

__device__ __forceinline__ float sigmoidf_dev(float x) {
    return 1.0f / (1.0f + expf(-x));
}

// Per-chunk local scan (zero init), store chunk-final value.
__global__ __launch_bounds__(256) void scan_partial(
    const float* __restrict__ gu, const float* __restrict__ lam, float* __restrict__ csum)
{
    const int s = threadIdx.x;
    const int chunk = blockIdx.x;   // 0..NCH-1
    const int b = blockIdx.y;       // 0..BB-1
    const float d = sigmoidf_dev(lam[s]);
    const float* p = gu + ((size_t)b * TT + (size_t)chunk * LCH) * DS + s;
    float h = 0.0f;
#pragma unroll
    for (int t = 0; t < LCH; t++) h = fmaf(d, h, p[(size_t)t * DS]);
    csum[((size_t)b * NCH + chunk) * DS + s] = h;
}

// Sequential scan over chunk partials; write carry-in per chunk and final state.
__global__ __launch_bounds__(256) void carry_scan(
    const float* __restrict__ csum, const float* __restrict__ state,
    const float* __restrict__ lam, float* __restrict__ carry, float* __restrict__ hlast)
{
    const int s = threadIdx.x;
    const int b = blockIdx.x;
    const float d = sigmoidf_dev(lam[s]);
    float dL = d;
#pragma unroll
    for (int i = 0; i < 5; i++) dL *= dL;   // d^32
    float H = state[(size_t)b * DS + s];
#pragma unroll 8
    for (int k = 0; k < NCH; k++) {
        carry[((size_t)b * NCH + k) * DS + s] = H;
        H = fmaf(dL, H, csum[((size_t)b * NCH + k) * DS + s]);
    }
    hlast[(size_t)b * DS + s] = H;
}

// Recompute local scan with the correct carry-in; overwrite gu in place with h.
__global__ __launch_bounds__(256) void scan_final(
    float* __restrict__ gu, const float* __restrict__ lam, const float* __restrict__ carry)
{
    const int s = threadIdx.x;
    const int chunk = blockIdx.x;
    const int b = blockIdx.y;
    const float d = sigmoidf_dev(lam[s]);
    float* p = gu + ((size_t)b * TT + (size_t)chunk * LCH) * DS + s;
    float h = carry[((size_t)b * NCH + chunk) * DS + s];
#pragma unroll
    for (int t = 0; t < LCH; t++) {
        h = fmaf(d, h, p[(size_t)t * DS]);
        p[(size_t)t * DS] = h;
    }
}

extern "C" void kernel_launch(void* const* d_in, const int* in_sizes, int n_in,
                              void* d_out, int out_size, void* d_ws, size_t ws_size,
                              hipStream_t stream) {
    const float* x     = (const float*)d_in[0];
    const float* state = (const float*)d_in[1];
    const float* W_in  = (const float*)d_in[2];
    const float* b_in  = (const float*)d_in[3];
    const float* lam   = (const float*)d_in[4];
    const float* gamma = (const float*)d_in[5];
    const float* W_out = (const float*)d_in[6];
    const float* b_out = (const float*)d_in[7];

    float* y     = (float*)d_out;
    float* hlast = y + (size_t)MROWS * DM;

    char* ws = (char*)d_ws;
    float* gu    = (float*)ws;                                   // 16 MB, becomes h in place
    float* csum  = (float*)(ws + (size_t)MROWS * DS * 4);        // 512 KB
    float* carry = (float*)(ws + (size_t)MROWS * DS * 4 + (size_t)BB * NCH * DS * 4);

    dim3 blk(256);

    // GEMM1: gu = gamma * (x @ W_in + b_in)
    sgemm_kernel<<<dim3(MROWS / BM, DS / BN), blk, 0, stream>>>(
        x, W_in, gu, MROWS, DS, DM, b_in, gamma);

    // chunked scan
    scan_partial<<<dim3(NCH, BB), blk, 0, stream>>>(gu, lam, csum);
    carry_scan<<<dim3(BB), blk, 0, stream>>>(csum, state, lam, carry, hlast);
    scan_final<<<dim3(NCH, BB), blk, 0, stream>>>(gu, lam, carry);

    // GEMM2: y = h @ W_out + b_out   (gu now holds h)
    sgemm_kernel<<<dim3(MROWS / BM, DM / BN), blk, 0, stream>>>(
        gu, W_out, y, MROWS, DM, DS, b_out, nullptr);
}

// Round 2
// 119.808 us; speedup vs baseline: 2.0720x; 2.0720x over previous
//
#include <hip/hip_runtime.h>
#include <hip/hip_bf16.h>
#include <math.h>

// Problem dims (fixed)
#define BB 4
#define TT 4096
#define DM 1024
#define DS 256
#define MROWS (BB*TT)        // 16384

// Scan chunking
#define LCH 32               // chunk length
#define NCH (TT/LCH)         // 128 chunks

// MFMA GEMM tiling
#define BM 128
#define BN 128
#define BK 32
#define ST 40                // LDS row stride in bf16 elems (pad 32 -> 40: conflict-free b128 reads)

typedef __attribute__((ext_vector_type(8))) short short8v;     // 8 bf16 (4 VGPR) MFMA operand
typedef __attribute__((ext_vector_type(8))) unsigned short ushort8v;
typedef __attribute__((ext_vector_type(4))) float float4v;

__device__ __forceinline__ unsigned short bf16_bits(float f) {
    __hip_bfloat16 b = __float2bfloat16(f);
    union { __hip_bfloat16 b; unsigned short u; } cv; cv.b = b; return cv.u;
}
__device__ __forceinline__ float bits_to_f32(unsigned short h) {
    union { unsigned int u; float f; } cv; cv.u = ((unsigned int)h) << 16; return cv.f;
}
__device__ __forceinline__ void split_bf16(float a, unsigned short& hi, unsigned short& lo) {
    hi = bf16_bits(a);
    lo = bf16_bits(a - bits_to_f32(hi));
}
__device__ __forceinline__ float sigmoidf_dev(float x) {
    return 1.0f / (1.0f + expf(-x));
}

// ---------------- weight pre-split: W[K][N] fp32 -> Bt{hi,lo}[N][K] bf16 ----------------
__global__ __launch_bounds__(256) void split_weight(
    const float* __restrict__ W, unsigned short* __restrict__ Bh,
    unsigned short* __restrict__ Bl, int K, int N)
{
    int idx = blockIdx.x * 256 + threadIdx.x;     // over N*K, coalesced writes
    int n = idx / K, k = idx - n * K;
    float a = W[(size_t)k * N + n];
    unsigned short hi, lo;
    split_bf16(a, hi, lo);
    Bh[idx] = hi;
    Bl[idx] = lo;
}

// ---------------- split-bf16 MFMA GEMM ----------------
// C[M][N] = epi(A[M][K] @ Bt[N][K]^T + bias[n]) ; epi scale optional (per-col)
// PRESPLIT=false: A from fp32 Af, split in-kernel.  PRESPLIT=true: A from Ahg/Alg bf16.
template<bool PRESPLIT>
__global__ __launch_bounds__(256) void mfma_gemm(
    const float* __restrict__ Af,
    const unsigned short* __restrict__ Ahg, const unsigned short* __restrict__ Alg,
    const unsigned short* __restrict__ Bhg, const unsigned short* __restrict__ Blg,
    float* __restrict__ C, int M, int N, int K,
    const float* __restrict__ bias, const float* __restrict__ scale)
{
    __shared__ unsigned short Ah[BM * ST], Al[BM * ST], Bh[BN * ST], Bl[BN * ST];

    const int tid  = threadIdx.x;
    const int lane = tid & 63;
    const int wv   = tid >> 6;
    const int wr   = wv >> 1;      // wave row 0..1 (64 rows each)
    const int wc   = wv & 1;       // wave col 0..1 (64 cols each)
    const int bm   = blockIdx.x, bn = blockIdx.y;

    const int lrow = lane & 15;
    const int kb   = (lane >> 4) * 8;   // K-base of this lane's fragment

    float4v acc[4][4] = {};

    for (int k0 = 0; k0 < K; k0 += BK) {
        if (k0) __syncthreads();

        // ---- stage A tile (128 x 32) ----
        if constexpr (!PRESPLIT) {
            const int r0 = tid >> 3;            // 0..31
            const int c4 = (tid & 7) * 4;       // 0..28
#pragma unroll
            for (int p = 0; p < 4; p++) {
                int row = r0 + p * 32;
                float4 v = *(const float4*)(Af + (size_t)(bm * BM + row) * K + k0 + c4);
                unsigned short h0,h1,h2,h3,l0,l1,l2,l3;
                split_bf16(v.x, h0, l0); split_bf16(v.y, h1, l1);
                split_bf16(v.z, h2, l2); split_bf16(v.w, h3, l3);
                *(ushort4*)&Ah[row * ST + c4] = make_ushort4(h0, h1, h2, h3);
                *(ushort4*)&Al[row * ST + c4] = make_ushort4(l0, l1, l2, l3);
            }
        } else {
            const int r0 = tid >> 2;            // 0..63
            const int c8 = (tid & 3) * 8;       // 0..24
#pragma unroll
            for (int p = 0; p < 2; p++) {
                int row = r0 + p * 64;
                size_t g = (size_t)(bm * BM + row) * K + k0 + c8;
                *(ushort8v*)&Ah[row * ST + c8] = *(const ushort8v*)(Ahg + g);
                *(ushort8v*)&Al[row * ST + c8] = *(const ushort8v*)(Alg + g);
            }
        }

        // ---- stage B tile (128 cols x 32 k), already [N][K] bf16 ----
        {
            const int r0 = tid >> 2;
            const int c8 = (tid & 3) * 8;
#pragma unroll
            for (int p = 0; p < 2; p++) {
                int row = r0 + p * 64;
                size_t g = (size_t)(bn * BN + row) * K + k0 + c8;
                *(ushort8v*)&Bh[row * ST + c8] = *(const ushort8v*)(Bhg + g);
                *(ushort8v*)&Bl[row * ST + c8] = *(const ushort8v*)(Blg + g);
            }
        }

        __syncthreads();

        // ---- fragments + MFMA ----
        short8v ah[4], al[4], bh[4], bl[4];
#pragma unroll
        for (int i = 0; i < 4; i++) {
            int r = wr * 64 + i * 16 + lrow;
            ah[i] = *(const short8v*)&Ah[r * ST + kb];
            al[i] = *(const short8v*)&Al[r * ST + kb];
        }
#pragma unroll
        for (int j = 0; j < 4; j++) {
            int r = wc * 64 + j * 16 + lrow;
            bh[j] = *(const short8v*)&Bh[r * ST + kb];
            bl[j] = *(const short8v*)&Bl[r * ST + kb];
        }
#pragma unroll
        for (int i = 0; i < 4; i++)
#pragma unroll
            for (int j = 0; j < 4; j++) {
                acc[i][j] = __builtin_amdgcn_mfma_f32_16x16x32_bf16(ah[i], bh[j], acc[i][j], 0, 0, 0);
                acc[i][j] = __builtin_amdgcn_mfma_f32_16x16x32_bf16(ah[i], bl[j], acc[i][j], 0, 0, 0);
                acc[i][j] = __builtin_amdgcn_mfma_f32_16x16x32_bf16(al[i], bh[j], acc[i][j], 0, 0, 0);
            }
    }

    // ---- epilogue: C[m][n] = (acc + bias[n]) * scale[n] ----
    const int rbl = (lane >> 4) * 4;
#pragma unroll
    for (int j = 0; j < 4; j++) {
        int col = bn * BN + wc * 64 + j * 16 + lrow;
        float bi = bias[col];
        float sc = scale ? scale[col] : 1.0f;
#pragma unroll
        for (int i = 0; i < 4; i++) {
            int r0 = bm * BM + wr * 64 + i * 16 + rbl;
#pragma unroll
            for (int reg = 0; reg < 4; reg++) {
                C[(size_t)(r0 + reg) * N + col] = (acc[i][j][reg] + bi) * sc;
            }
        }
    }
}

// ---------------- scan kernels ----------------
__global__ __launch_bounds__(256) void scan_partial(
    const float* __restrict__ gu, const float* __restrict__ lam, float* __restrict__ csum)
{
    const int s = threadIdx.x;
    const int chunk = blockIdx.x;
    const int b = blockIdx.y;
    const float d = sigmoidf_dev(lam[s]);
    const float* p = gu + ((size_t)b * TT + (size_t)chunk * LCH) * DS + s;
    float h = 0.0f;
#pragma unroll
    for (int t = 0; t < LCH; t++) h = fmaf(d, h, p[(size_t)t * DS]);
    csum[((size_t)b * NCH + chunk) * DS + s] = h;
}

__global__ __launch_bounds__(256) void carry_scan(
    const float* __restrict__ csum, const float* __restrict__ state,
    const float* __restrict__ lam, float* __restrict__ carry, float* __restrict__ hlast)
{
    const int s = threadIdx.x;
    const int b = blockIdx.x;
    const float d = sigmoidf_dev(lam[s]);
    float dL = d;
#pragma unroll
    for (int i = 0; i < 5; i++) dL *= dL;   // d^32
    float H = state[(size_t)b * DS + s];
#pragma unroll 8
    for (int k = 0; k < NCH; k++) {
        carry[((size_t)b * NCH + k) * DS + s] = H;
        H = fmaf(dL, H, csum[((size_t)b * NCH + k) * DS + s]);
    }
    hlast[(size_t)b * DS + s] = H;
}

// recompute with carry; emit h as split bf16 hi/lo (feeds GEMM2 directly)
__global__ __launch_bounds__(256) void scan_final(
    const float* __restrict__ gu, const float* __restrict__ lam,
    const float* __restrict__ carry,
    unsigned short* __restrict__ hhi, unsigned short* __restrict__ hlo)
{
    const int s = threadIdx.x;
    const int chunk = blockIdx.x;
    const int b = blockIdx.y;
    const float d = sigmoidf_dev(lam[s]);
    const size_t base = ((size_t)b * TT + (size_t)chunk * LCH) * DS + s;
    const float* p = gu + base;
    unsigned short* ph = hhi + base;
    unsigned short* pl = hlo + base;
    float h = carry[((size_t)b * NCH + chunk) * DS + s];
#pragma unroll
    for (int t = 0; t < LCH; t++) {
        h = fmaf(d, h, p[(size_t)t * DS]);
        unsigned short hi, lo;
        split_bf16(h, hi, lo);
        ph[(size_t)t * DS] = hi;
        pl[(size_t)t * DS] = lo;
    }
}

extern "C" void kernel_launch(void* const* d_in, const int* in_sizes, int n_in,
                              void* d_out, int out_size, void* d_ws, size_t ws_size,
                              hipStream_t stream) {
    const float* x     = (const float*)d_in[0];
    const float* state = (const float*)d_in[1];
    const float* W_in  = (const float*)d_in[2];
    const float* b_in  = (const float*)d_in[3];
    const float* lam   = (const float*)d_in[4];
    const float* gamma = (const float*)d_in[5];
    const float* W_out = (const float*)d_in[6];
    const float* b_out = (const float*)d_in[7];

    float* y     = (float*)d_out;
    float* hlast = y + (size_t)MROWS * DM;

    char* ws = (char*)d_ws;
    const size_t MB = 1024 * 1024;
    float*          gu    = (float*)(ws);                       // 16 MB
    float*          csum  = (float*)(ws + 16 * MB);             // 512 KB
    float*          carry = (float*)(ws + 16 * MB + 512 * 1024);// 512 KB
    unsigned short* hhi   = (unsigned short*)(ws + 17 * MB);    // 8 MB
    unsigned short* hlo   = (unsigned short*)(ws + 25 * MB);    // 8 MB
    unsigned short* w1hi  = (unsigned short*)(ws + 33 * MB);    // 512 KB  [DS][DM]
    unsigned short* w1lo  = (unsigned short*)(ws + 33 * MB + 512 * 1024);
    unsigned short* w2hi  = (unsigned short*)(ws + 34 * MB);    // 512 KB  [DM][DS]
    unsigned short* w2lo  = (unsigned short*)(ws + 34 * MB + 512 * 1024);

    dim3 blk(256);

    // pre-split weights (transposed to [N][K] bf16 hi/lo)
    split_weight<<<dim3((DS * DM) / 256), blk, 0, stream>>>(W_in,  w1hi, w1lo, DM, DS);
    split_weight<<<dim3((DS * DM) / 256), blk, 0, stream>>>(W_out, w2hi, w2lo, DS, DM);

    // GEMM1: gu = gamma * (x @ W_in + b_in)   [16384 x 256], K=1024
    mfma_gemm<false><<<dim3(MROWS / BM, DS / BN), blk, 0, stream>>>(
        x, nullptr, nullptr, w1hi, w1lo, gu, MROWS, DS, DM, b_in, gamma);

    // chunked scan over T
    scan_partial<<<dim3(NCH, BB), blk, 0, stream>>>(gu, lam, csum);
    carry_scan<<<dim3(BB), blk, 0, stream>>>(csum, state, lam, carry, hlast);
    scan_final<<<dim3(NCH, BB), blk, 0, stream>>>(gu, lam, carry, hhi, hlo);

    // GEMM2: y = h @ W_out + b_out   [16384 x 1024], K=256  (A pre-split)
    mfma_gemm<true><<<dim3(MROWS / BM, DM / BN), blk, 0, stream>>>(
        nullptr, hhi, hlo, w2hi, w2lo, y, MROWS, DM, DS, b_out, nullptr);
}

// Round 3
// 106.838 us; speedup vs baseline: 2.3236x; 1.1214x over previous
//
#include <hip/hip_runtime.h>
#include <hip/hip_bf16.h>
#include <math.h>

// Problem dims (fixed)
#define BB 4
#define TT 4096
#define DM 1024
#define DS 256
#define MROWS (BB*TT)        // 16384

// Scan chunking
#define LCH 32
#define NCH (TT/LCH)         // 128

// MFMA GEMM tiling: 128x64 tile, BK=32, 4 waves (2x2), per-wave 64x32 = 4x2 frags
#define BM 128
#define BN 64
#define BK 32
#define ST 40                // LDS row stride (bf16 elems); frag reads min-aliased, writes 2-way

typedef __attribute__((ext_vector_type(8))) short short8v;
typedef __attribute__((ext_vector_type(8))) unsigned short ushort8v;
typedef __attribute__((ext_vector_type(4))) float float4v;

__device__ __forceinline__ unsigned short bf16_bits(float f) {
    union { __hip_bfloat16 b; unsigned short u; } cv;
    cv.b = __float2bfloat16(f);
    return cv.u;
}
__device__ __forceinline__ float bits_to_f32(unsigned short h) {
    union { unsigned int u; float f; } cv; cv.u = ((unsigned int)h) << 16; return cv.f;
}
__device__ __forceinline__ void split_bf16(float a, unsigned short& hi, unsigned short& lo) {
    hi = bf16_bits(a);
    lo = bf16_bits(a - bits_to_f32(hi));
}
__device__ __forceinline__ float sigmoidf_dev(float x) {
    return 1.0f / (1.0f + expf(-x));
}

// ---------------- weight pre-split: W[K][N] fp32 -> Bt{hi,lo}[N][K] bf16 ----------------
__global__ __launch_bounds__(256) void split_weight(
    const float* __restrict__ W, unsigned short* __restrict__ Bh,
    unsigned short* __restrict__ Bl, int K, int N)
{
    int idx = blockIdx.x * 256 + threadIdx.x;
    int n = idx / K, k = idx - n * K;
    float a = W[(size_t)k * N + n];
    unsigned short hi, lo;
    split_bf16(a, hi, lo);
    Bh[idx] = hi;
    Bl[idx] = lo;
}

// ---------------- split-bf16 MFMA GEMM, software-pipelined, LDS double-buffered ----------
// C[M][N] = (A[M][K] @ Bt[N][K]^T + bias[n]) * scale[n]
// PRESPLIT=false: A fp32 (split in-kernel). PRESPLIT=true: A pre-split bf16 hi/lo.
template<bool PRESPLIT>
__global__ __launch_bounds__(256) void mfma_gemm(
    const float* __restrict__ Af,
    const unsigned short* __restrict__ Ahg, const unsigned short* __restrict__ Alg,
    const unsigned short* __restrict__ Bhg, const unsigned short* __restrict__ Blg,
    float* __restrict__ C, int M, int N, int K,
    const float* __restrict__ bias, const float* __restrict__ scale)
{
    __shared__ unsigned short Ah[2][BM * ST], Al[2][BM * ST];
    __shared__ unsigned short Bh[2][BN * ST], Bl[2][BN * ST];

    const int tid  = threadIdx.x;
    const int lane = tid & 63;
    const int wv   = tid >> 6;
    const int wr   = wv >> 1;           // 0..1, 64 rows each
    const int wc   = wv & 1;            // 0..1, 32 cols each
    const int bm   = blockIdx.x, bn = blockIdx.y;

    const int lrow = lane & 15;
    const int kb   = (lane >> 4) * 8;

    // staging indices: chunks of 8 elems along K
    const int ar0 = tid >> 2;           // A rows ar0, ar0+64
    const int ac8 = (tid & 3) * 8;
    const int br0 = tid >> 2;           // B row (one chunk per thread)
    const int bc8 = (tid & 3) * 8;

    const int NT = K / BK;
    float4v acc[4][2] = {};

    // staged registers for next tile
    float4    af_s[2][2];               // PRESPLIT=false: 2 rows x 8 floats
    ushort8v  ah_s[2], al_s[2];         // PRESPLIT=true
    ushort8v  bh_s, bl_s;

#define LOADS(T)                                                                  \
    do {                                                                          \
        const int k0_ = (T) * BK;                                                 \
        if constexpr (!PRESPLIT) {                                                \
            _Pragma("unroll")                                                     \
            for (int p = 0; p < 2; p++) {                                         \
                size_t g = (size_t)(bm * BM + ar0 + 64 * p) * K + k0_ + ac8;      \
                af_s[p][0] = *(const float4*)(Af + g);                            \
                af_s[p][1] = *(const float4*)(Af + g + 4);                        \
            }                                                                     \
        } else {                                                                  \
            _Pragma("unroll")                                                     \
            for (int p = 0; p < 2; p++) {                                         \
                size_t g = (size_t)(bm * BM + ar0 + 64 * p) * K + k0_ + ac8;      \
                ah_s[p] = *(const ushort8v*)(Ahg + g);                            \
                al_s[p] = *(const ushort8v*)(Alg + g);                            \
            }                                                                     \
        }                                                                         \
        {                                                                         \
            size_t g = (size_t)(bn * BN + br0) * K + k0_ + bc8;                   \
            bh_s = *(const ushort8v*)(Bhg + g);                                   \
            bl_s = *(const ushort8v*)(Blg + g);                                   \
        }                                                                         \
    } while (0)

#define WRITES(Wb)                                                                \
    do {                                                                          \
        if constexpr (!PRESPLIT) {                                                \
            _Pragma("unroll")                                                     \
            for (int p = 0; p < 2; p++) {                                         \
                float f[8] = {af_s[p][0].x, af_s[p][0].y, af_s[p][0].z,           \
                              af_s[p][0].w, af_s[p][1].x, af_s[p][1].y,           \
                              af_s[p][1].z, af_s[p][1].w};                        \
                ushort8v h, l;                                                    \
                _Pragma("unroll")                                                 \
                for (int e = 0; e < 8; e++) {                                     \
                    unsigned short hu, lu;                                        \
                    split_bf16(f[e], hu, lu);                                     \
                    h[e] = hu; l[e] = lu;                                         \
                }                                                                 \
                *(ushort8v*)&Ah[Wb][(ar0 + 64 * p) * ST + ac8] = h;               \
                *(ushort8v*)&Al[Wb][(ar0 + 64 * p) * ST + ac8] = l;               \
            }                                                                     \
        } else {                                                                  \
            _Pragma("unroll")                                                     \
            for (int p = 0; p < 2; p++) {                                         \
                *(ushort8v*)&Ah[Wb][(ar0 + 64 * p) * ST + ac8] = ah_s[p];         \
                *(ushort8v*)&Al[Wb][(ar0 + 64 * p) * ST + ac8] = al_s[p];         \
            }                                                                     \
        }                                                                         \
        *(ushort8v*)&Bh[Wb][br0 * ST + bc8] = bh_s;                               \
        *(ushort8v*)&Bl[Wb][br0 * ST + bc8] = bl_s;                               \
    } while (0)

    // prologue: stage tile 0 into buffer 0
    LOADS(0);
    WRITES(0);
    __syncthreads();

    for (int t = 0; t < NT; ++t) {
        const int R = t & 1, W = R ^ 1;
        const bool more = (t + 1 < NT);
        if (more) LOADS(t + 1);

        // fragments + MFMA on buf[R]
        short8v ah[4], al[4], bh[2], bl[2];
#pragma unroll
        for (int i = 0; i < 4; i++) {
            int r = wr * 64 + i * 16 + lrow;
            ah[i] = *(const short8v*)&Ah[R][r * ST + kb];
            al[i] = *(const short8v*)&Al[R][r * ST + kb];
        }
#pragma unroll
        for (int j = 0; j < 2; j++) {
            int r = wc * 32 + j * 16 + lrow;
            bh[j] = *(const short8v*)&Bh[R][r * ST + kb];
            bl[j] = *(const short8v*)&Bl[R][r * ST + kb];
        }
#pragma unroll
        for (int i = 0; i < 4; i++)
#pragma unroll
            for (int j = 0; j < 2; j++) {
                acc[i][j] = __builtin_amdgcn_mfma_f32_16x16x32_bf16(ah[i], bh[j], acc[i][j], 0, 0, 0);
                acc[i][j] = __builtin_amdgcn_mfma_f32_16x16x32_bf16(ah[i], bl[j], acc[i][j], 0, 0, 0);
                acc[i][j] = __builtin_amdgcn_mfma_f32_16x16x32_bf16(al[i], bh[j], acc[i][j], 0, 0, 0);
            }

        if (more) {
            WRITES(W);
            __syncthreads();
        }
    }

    // epilogue
    const int rbl = (lane >> 4) * 4;
#pragma unroll
    for (int j = 0; j < 2; j++) {
        int col = bn * BN + wc * 32 + j * 16 + lrow;
        float bi = bias[col];
        float sc = scale ? scale[col] : 1.0f;
#pragma unroll
        for (int i = 0; i < 4; i++) {
            int r0 = bm * BM + wr * 64 + i * 16 + rbl;
#pragma unroll
            for (int reg = 0; reg < 4; reg++) {
                C[(size_t)(r0 + reg) * N + col] = (acc[i][j][reg] + bi) * sc;
            }
        }
    }
#undef LOADS
#undef WRITES
}

// ---------------- scan kernels ----------------
__global__ __launch_bounds__(256) void scan_partial(
    const float* __restrict__ gu, const float* __restrict__ lam, float* __restrict__ csum)
{
    const int s = threadIdx.x;
    const int chunk = blockIdx.x;
    const int b = blockIdx.y;
    const float d = sigmoidf_dev(lam[s]);
    const float* p = gu + ((size_t)b * TT + (size_t)chunk * LCH) * DS + s;
    float h = 0.0f;
#pragma unroll
    for (int t = 0; t < LCH; t++) h = fmaf(d, h, p[(size_t)t * DS]);
    csum[((size_t)b * NCH + chunk) * DS + s] = h;
}

__global__ __launch_bounds__(256) void carry_scan(
    const float* __restrict__ csum, const float* __restrict__ state,
    const float* __restrict__ lam, float* __restrict__ carry, float* __restrict__ hlast)
{
    const int s = threadIdx.x;
    const int b = blockIdx.x;
    const float d = sigmoidf_dev(lam[s]);
    float dL = d;
#pragma unroll
    for (int i = 0; i < 5; i++) dL *= dL;   // d^32
    float H = state[(size_t)b * DS + s];
#pragma unroll 8
    for (int k = 0; k < NCH; k++) {
        carry[((size_t)b * NCH + k) * DS + s] = H;
        H = fmaf(dL, H, csum[((size_t)b * NCH + k) * DS + s]);
    }
    hlast[(size_t)b * DS + s] = H;
}

__global__ __launch_bounds__(256) void scan_final(
    const float* __restrict__ gu, const float* __restrict__ lam,
    const float* __restrict__ carry,
    unsigned short* __restrict__ hhi, unsigned short* __restrict__ hlo)
{
    const int s = threadIdx.x;
    const int chunk = blockIdx.x;
    const int b = blockIdx.y;
    const float d = sigmoidf_dev(lam[s]);
    const size_t base = ((size_t)b * TT + (size_t)chunk * LCH) * DS + s;
    const float* p = gu + base;
    unsigned short* ph = hhi + base;
    unsigned short* pl = hlo + base;
    float h = carry[((size_t)b * NCH + chunk) * DS + s];
#pragma unroll
    for (int t = 0; t < LCH; t++) {
        h = fmaf(d, h, p[(size_t)t * DS]);
        unsigned short hi, lo;
        split_bf16(h, hi, lo);
        ph[(size_t)t * DS] = hi;
        pl[(size_t)t * DS] = lo;
    }
}

extern "C" void kernel_launch(void* const* d_in, const int* in_sizes, int n_in,
                              void* d_out, int out_size, void* d_ws, size_t ws_size,
                              hipStream_t stream) {
    const float* x     = (const float*)d_in[0];
    const float* state = (const float*)d_in[1];
    const float* W_in  = (const float*)d_in[2];
    const float* b_in  = (const float*)d_in[3];
    const float* lam   = (const float*)d_in[4];
    const float* gamma = (const float*)d_in[5];
    const float* W_out = (const float*)d_in[6];
    const float* b_out = (const float*)d_in[7];

    float* y     = (float*)d_out;
    float* hlast = y + (size_t)MROWS * DM;

    char* ws = (char*)d_ws;
    const size_t MB = 1024 * 1024;
    float*          gu    = (float*)(ws);                        // 16 MB
    float*          csum  = (float*)(ws + 16 * MB);              // 512 KB
    float*          carry = (float*)(ws + 16 * MB + 512 * 1024); // 512 KB
    unsigned short* hhi   = (unsigned short*)(ws + 17 * MB);     // 8 MB
    unsigned short* hlo   = (unsigned short*)(ws + 25 * MB);     // 8 MB
    unsigned short* w1hi  = (unsigned short*)(ws + 33 * MB);     // [DS][DM]
    unsigned short* w1lo  = (unsigned short*)(ws + 33 * MB + 512 * 1024);
    unsigned short* w2hi  = (unsigned short*)(ws + 34 * MB);     // [DM][DS]
    unsigned short* w2lo  = (unsigned short*)(ws + 34 * MB + 512 * 1024);

    dim3 blk(256);

    split_weight<<<dim3((DS * DM) / 256), blk, 0, stream>>>(W_in,  w1hi, w1lo, DM, DS);
    split_weight<<<dim3((DS * DM) / 256), blk, 0, stream>>>(W_out, w2hi, w2lo, DS, DM);

    // GEMM1: gu = gamma * (x @ W_in + b_in)   [16384 x 256], K=1024, grid 512
    mfma_gemm<false><<<dim3(MROWS / BM, DS / BN), blk, 0, stream>>>(
        x, nullptr, nullptr, w1hi, w1lo, gu, MROWS, DS, DM, b_in, gamma);

    scan_partial<<<dim3(NCH, BB), blk, 0, stream>>>(gu, lam, csum);
    carry_scan<<<dim3(BB), blk, 0, stream>>>(csum, state, lam, carry, hlast);
    scan_final<<<dim3(NCH, BB), blk, 0, stream>>>(gu, lam, carry, hhi, hlo);

    // GEMM2: y = h @ W_out + b_out   [16384 x 1024], K=256, grid 2048
    mfma_gemm<true><<<dim3(MROWS / BM, DM / BN), blk, 0, stream>>>(
        nullptr, hhi, hlo, w2hi, w2lo, y, MROWS, DM, DS, b_out, nullptr);
}